// Round 2
// baseline (230.018 us; speedup 1.0000x reference)
//
#include <hip/hip_runtime.h>
#include <hip/hip_cooperative_groups.h>
#include <hip/hip_bf16.h>
#include <stdint.h>

namespace cg = cooperative_groups;

typedef unsigned short ushort_t;
typedef unsigned long long u64;
typedef __attribute__((ext_vector_type(8))) short short8;   // 8 bf16 (4 VGPRs)
typedef __attribute__((ext_vector_type(4))) float f32x4;

#define N_NODES 384
#define HF      512
#define IT      12        // i-rows per attention tile: 32 tiles x 8 heads = 256

__device__ inline ushort_t f2bf(float f) {
  __hip_bfloat16 b = __float2bfloat16(f);
  return *reinterpret_cast<ushort_t*>(&b);
}
__device__ inline float bf2f_u(ushort_t u) {
  union { float f; uint32_t i; } v; v.i = ((uint32_t)u) << 16; return v.f;
}
__device__ inline short8 pack8(const float* s) {
  short8 r;
#pragma unroll
  for (int j = 0; j < 8; ++j) r[j] = (short)f2bf(s[j]);
  return r;
}

// Shared-memory layout for the attention phases (single instance at kernel
// scope so the two template instantiations don't double-allocate LDS).
// Total: 49152 + 18432 + 12544 + 48 + 576 = 80752 B -> 1 block/CU.
struct SMem {
  __align__(16) char gl_raw[49152];      // s_gl (DMA dst only) [384][64] bf16
  float    e[IT][N_NODES];               // scores
  ushort_t pb[16][392];                  // normalized P, bf16, padded rows
  float    bri[IT];
  u64      mask[IT][6];
};

// ---------------------------------------------------------------------------
// GEMM phase (R14: fused form of R10's gemm_direct, fp32-direct operands —
// R13 showed the bf16-prepack path is neutral, so the extra kernel was
// reverted). 1536 wave-tiles of 16m x 16n over 24 x 64; tile = bx*6 + wave,
// so waves of one block share A-rows (L1 reuse), same per-wave load pattern
// as R10 (2 x float4 A + 8 scalar W rows per kc).
//  n <  512 (gl): glb bf16 [m][n]
//  n >= 512 (gr): G fp32 [m][512+n'] and grT bf16 [n'][m] (k-contig)
// Layer 0 extra: adjacency bitmasks (blocks 0..63, one row per wave).
// ---------------------------------------------------------------------------
__device__ __forceinline__ void gemm_phase(
    const float* __restrict__ X, const float* __restrict__ WL,
    const float* __restrict__ WR, float* __restrict__ G,
    ushort_t* __restrict__ glb, ushort_t* __restrict__ grT,
    const int* __restrict__ adj, u64* __restrict__ mbits)
{
  const int t = threadIdx.x, wave = t >> 6, lane = t & 63;
  const int lm = lane & 15, q = lane >> 4;
  const int tile = blockIdx.x * 6 + wave;        // [0, 1536)
  const int m0 = (tile >> 6) * 16;               // 24 m-tiles
  const int n0 = (tile & 63) * 16;               // 64 n-tiles
  const float* Wp = (n0 < 512) ? (WL + n0) : (WR + (n0 - 512));
  const float* Arow = X + (m0 + lm) * HF;

  f32x4 acc = {0.f, 0.f, 0.f, 0.f};
#pragma unroll 4
  for (int kc = 0; kc < 16; ++kc) {
    const int kbase = kc * 32 + q * 8;
    float4 a0 = *(const float4*)(Arow + kbase);
    float4 a1 = *(const float4*)(Arow + kbase + 4);
    float av8[8] = {a0.x, a0.y, a0.z, a0.w, a1.x, a1.y, a1.z, a1.w};
    short8 af = pack8(av8);
    float bf[8];
#pragma unroll
    for (int j = 0; j < 8; ++j) bf[j] = Wp[(kbase + j) * HF + lm];
    short8 b = pack8(bf);
    acc = __builtin_amdgcn_mfma_f32_16x16x32_bf16(af, b, acc, 0, 0, 0);
  }
  if (n0 < 512) {
#pragma unroll
    for (int r = 0; r < 4; ++r) {
      int m = m0 + q * 4 + r;
      glb[m * HF + n0 + lm] = f2bf(acc[r]);
    }
  } else {
#pragma unroll
    for (int r = 0; r < 4; ++r) {
      int m = m0 + q * 4 + r;
      G[m * 1024 + n0 + lm] = acc[r];
    }
    int c0 = n0 - 512;
    uint2 p;
    p.x = (uint32_t)f2bf(acc[0]) | ((uint32_t)f2bf(acc[1]) << 16);
    p.y = (uint32_t)f2bf(acc[2]) | ((uint32_t)f2bf(acc[3]) << 16);
    *(uint2*)&grT[(c0 + lm) * 384 + m0 + q * 4] = p;
  }
  // layer-0 only: adjacency bitmasks (self-loop OR'd in)
  if (adj != nullptr && blockIdx.x < 64) {
    int row = blockIdx.x * 6 + wave;             // [0, 384)
#pragma unroll
    for (int w = 0; w < 6; ++w) {
      int j = w * 64 + lane;
      u64 m = __ballot(adj[row * N_NODES + j] != 0 || row == j);
      if (lane == 0) mbits[row * 6 + w] = m;
    }
  }
}

// ---------------------------------------------------------------------------
// Attention phase (R10 + 3-barrier restructure, unchanged logic; R14 adds a
// 4-accumulator phase-1 to break the 64-deep serial FMA chain).
// Block = (i-tile, head): it = bx & 31, h = bx >> 5.
// ---------------------------------------------------------------------------
template <int LAYER>
__device__ __forceinline__ void attn_phase(
    SMem& sm, const float* __restrict__ G, const ushort_t* __restrict__ glb,
    const ushort_t* __restrict__ grT, const u64* __restrict__ mbits,
    const float* __restrict__ resid_in, const float* __restrict__ avec,
    float* __restrict__ xcur_out, float* __restrict__ f_out)
{
  ushort_t (*s_gl)[64] = (ushort_t(*)[64])sm.gl_raw;
  const int t = threadIdx.x;
  const int i0 = (blockIdx.x & 31) * IT, h = blockIdx.x >> 5;
  const int lane = t & 63, wave = t >> 6;
  const int lm = lane & 15, q = lane >> 4;

  // -- issue async global->LDS DMA first (8 x 16 B per thread) --
#pragma unroll
  for (int rep = 0; rep < 8; ++rep) {
    int idx = rep * 384 + t, row = idx >> 3, cl = idx & 7;
    int cg = cl ^ (row & 7);
    const ushort_t* gsrc = glb + row * HF + h * 64 + cg * 8;
    __builtin_amdgcn_global_load_lds(
        (const __attribute__((address_space(1))) uint32_t*)gsrc,
        (__attribute__((address_space(3))) uint32_t*)(sm.gl_raw + idx * 16),
        16, 0, 0);
  }

  // -- prefetch phase-3 B-fragments + epilogue resid (independent loads) --
  short8 bfrag[12];
  float  rres[4];
  if (wave < 4) {
    const ushort_t* Brow = grT + (h * 64 + wave * 16 + lm) * 384;
#pragma unroll
    for (int kc = 0; kc < 12; ++kc)
      bfrag[kc] = *(const short8*)&Brow[kc * 32 + q * 8];
    if (q < 3) {
#pragma unroll
      for (int r = 0; r < 4; ++r)
        rres[r] = resid_in[(i0 + q * 4 + r) * HF + h * 64 + wave * 16 + lm];
    }
  }

  // -- overlapped with DMA: masks (72 u64) + bri dot + s_pb pad zeroing --
  if (t < 72) ((u64*)sm.mask)[t] = mbits[i0 * 6 + t];
  if (t >= 128 && t < 320) {
    int u = t - 128, il = u >> 4, fg = u & 15;
    float4 g4 = *(const float4*)(G + (i0 + il) * 1024 + 512 + h * 64 + fg * 4);
    float4 a4 = *(const float4*)(avec + fg * 4);
    float s = a4.x * g4.x + a4.y * g4.y + a4.z * g4.z + a4.w * g4.w;
    s += __shfl_xor(s, 1); s += __shfl_xor(s, 2);
    s += __shfl_xor(s, 4); s += __shfl_xor(s, 8);
    if (fg == 0) sm.bri[il] = s;
  }
#pragma unroll
  for (int r4 = 0; r4 < 4; ++r4) sm.pb[IT + r4][t] = 0;  // zero P rows 12..15
  __syncthreads();   // barrier 1: drains DMA + overlap work

  // -- own j-row -> 64 VGPRs (chunk cg at slot cg^(t&7)); avec -> VGPRs --
  float gl[64], av[64];
  {
    const int sw = t & 7;
#pragma unroll
    for (int cg = 0; cg < 8; ++cg) {
      short8 v = *(const short8*)&s_gl[t][(cg ^ sw) * 8];
#pragma unroll
      for (int u2 = 0; u2 < 8; ++u2)
        gl[cg * 8 + u2] = bf2f_u((ushort_t)v[u2]);
    }
#pragma unroll
    for (int c = 0; c < 16; ++c) {
      float4 a4 = ((const float4*)avec)[c];
      av[c * 4] = a4.x; av[c * 4 + 1] = a4.y;
      av[c * 4 + 2] = a4.z; av[c * 4 + 3] = a4.w;
    }
  }
  float accl = 0.f;
#pragma unroll
  for (int f = 0; f < 64; ++f) accl += av[f] * gl[f];
  // no barrier: s_e is a separate region; each thread writes its own column

  // -- phase 1: scores, written straight to LDS (4 acc chains for latency) --
  const int jw = t >> 6, jb = t & 63;
#pragma unroll
  for (int il = 0; il < IT; ++il) {
    const float4* gr4 = (const float4*)(G + (i0 + il) * 1024 + 512 + h * 64);
    float c0 = 0.f, c1 = 0.f, c2 = 0.f, c3 = 0.f;
#pragma unroll
    for (int c = 0; c < 16; ++c) {
      float4 g4 = gr4[c];
      c0 += av[c * 4]     * fabsf(gl[c * 4]     + g4.x);
      c1 += av[c * 4 + 1] * fabsf(gl[c * 4 + 1] + g4.y);
      c2 += av[c * 4 + 2] * fabsf(gl[c * 4 + 2] + g4.z);
      c3 += av[c * 4 + 3] * fabsf(gl[c * 4 + 3] + g4.w);
    }
    float acc = (c0 + c1) + (c2 + c3);
    bool m = (sm.mask[il][jw] >> jb) & 1;
    float e = 0.6f * (accl + sm.bri[il]) + 0.4f * acc;
    sm.e[il][t] = m ? e : -1e30f;
  }
  __syncthreads();   // barrier 2: scores visible to softmax waves

  // -- phase 2: softmax over j per row; write normalized P bf16 --
#pragma unroll
  for (int rep = 0; rep < 2; ++rep) {
    int il = wave * 2 + rep;
    float v[6];
    float mx = -1e30f;
#pragma unroll
    for (int c = 0; c < 6; ++c) { v[c] = sm.e[il][lane + 64 * c]; mx = fmaxf(mx, v[c]); }
#pragma unroll
    for (int off = 32; off; off >>= 1) mx = fmaxf(mx, __shfl_xor(mx, off));
    float sum = 0.f;
#pragma unroll
    for (int c = 0; c < 6; ++c) { v[c] = __expf(v[c] - mx); sum += v[c]; }
#pragma unroll
    for (int off = 32; off; off >>= 1) sum += __shfl_xor(sum, off);
    float inv = 1.0f / sum;
#pragma unroll
    for (int c = 0; c < 6; ++c) sm.pb[il][lane + 64 * c] = f2bf(v[c] * inv);
  }
  __syncthreads();   // barrier 3: P visible to MFMA waves

  // -- phase 3: MFMA (A from LDS, B + resid already in registers) --
  if (wave < 4) {
    f32x4 acc = {0.f, 0.f, 0.f, 0.f};
#pragma unroll
    for (int kc = 0; kc < 12; ++kc) {
      short8 af = *(const short8*)&sm.pb[lm][kc * 32 + q * 8];
      acc = __builtin_amdgcn_mfma_f32_16x16x32_bf16(af, bfrag[kc], acc, 0, 0, 0);
    }
    if (q < 3) {                                    // D rows 0..11
#pragma unroll
      for (int r = 0; r < 4; ++r) {
        int i = i0 + q * 4 + r;
        int off = i * HF + h * 64 + wave * 16 + lm;
        float o = acc[r];
        if (LAYER == 0) {
          float oe = (o > 0.f) ? o : (__expf(o) - 1.f);   // ELU
          xcur_out[off] = rres[r] + oe;   // fp32 residual for layer 1
        } else {
          f_out[off] = rres[r] + o;       // final output, fp32
        }
      }
    }
  }
}

// ---------------------------------------------------------------------------
// R14: single cooperative kernel — gemm0 | sync | attn0 | sync | gemm1 |
// sync | attn1. Replaces 5 dispatches (R13) / 4 dispatches (R10) with one;
// inter-phase visibility via cg grid sync (device-scope fences). 256 blocks
// x 384 thr, 78.9 KB LDS -> exactly 1 block/CU, all co-resident.
// ---------------------------------------------------------------------------
__global__ __launch_bounds__(384) void gat_fused(
    const float* __restrict__ x, const int* __restrict__ adj,
    const float* __restrict__ Wl0, const float* __restrict__ Wr0,
    const float* __restrict__ a0, const float* __restrict__ Wl1,
    const float* __restrict__ Wr1, const float* __restrict__ a1,
    float* __restrict__ G, ushort_t* __restrict__ glb,
    ushort_t* __restrict__ grT, u64* __restrict__ mbits,
    float* __restrict__ xcur, float* __restrict__ out)
{
  __shared__ SMem sm;
  cg::grid_group grid = cg::this_grid();

  gemm_phase(x, Wl0, Wr0, G, glb, grT, adj, mbits);
  grid.sync();
  attn_phase<0>(sm, G, glb, grT, mbits, x, a0, xcur, nullptr);
  grid.sync();
  gemm_phase(xcur, Wl1, Wr1, G, glb, grT, nullptr, nullptr);
  grid.sync();
  attn_phase<1>(sm, G, glb, grT, mbits, xcur, a1, nullptr, out);
}

// ---------------------------------------------------------------------------
extern "C" void kernel_launch(void* const* d_in, const int* in_sizes, int n_in,
                              void* d_out, int out_size, void* d_ws, size_t ws_size,
                              hipStream_t stream) {
  const float* x   = (const float*)d_in[0];
  const int*   adj = (const int*)d_in[1];
  const float* Wl0 = (const float*)d_in[2];
  const float* Wr0 = (const float*)d_in[3];
  const float* a0  = (const float*)d_in[4];
  const float* Wl1 = (const float*)d_in[5];
  const float* Wr1 = (const float*)d_in[6];
  const float* a1  = (const float*)d_in[7];
  float* out = (float*)d_out;

  char* ws = (char*)d_ws;
  float*    G    = (float*)   (ws + 0L);            // 1.5 MB (gr half used)
  ushort_t* grT  = (ushort_t*)(ws + (2L << 20));    // 384 KB gr^T bf16
  ushort_t* glb  = (ushort_t*)(ws + (3L << 20));    // 384 KB gl bf16
  u64*      mbits= (u64*)     (ws + (4L << 20));    // 18 KB adjacency bits
  float*    xcur = (float*)   (ws + (5L << 20));    // 768 KB fp32 residual

  void* args[] = {&x, &adj, &Wl0, &Wr0, &a0, &Wl1, &Wr1, &a1,
                  &G, &glb, &grT, &mbits, &xcur, &out};
  hipLaunchCooperativeKernel((void*)gat_fused, dim3(256), dim3(384), args,
                             0, stream);
}

// Round 4
// 126.104 us; speedup vs baseline: 1.8240x; 1.8240x over previous
//
#include <hip/hip_runtime.h>
#include <hip/hip_bf16.h>
#include <stdint.h>

typedef unsigned short ushort_t;
typedef unsigned long long u64;
typedef __attribute__((ext_vector_type(8))) short short8;   // 8 bf16 (4 VGPRs)
typedef __attribute__((ext_vector_type(4))) float f32x4;

#define N_NODES 384
#define HF      512
#define IT      6         // i-rows per attention block: 64 tiles x 8 heads
                          // R16: halved from 12 -> LDS 69.6 KB -> 2 blocks/CU

__device__ inline ushort_t f2bf(float f) {
  __hip_bfloat16 b = __float2bfloat16(f);
  return *reinterpret_cast<ushort_t*>(&b);
}
__device__ inline float bf2f_u(ushort_t u) {
  union { float f; uint32_t i; } v; v.i = ((uint32_t)u) << 16; return v.f;
}
__device__ inline short8 pack8(const float* s) {
  short8 r;
#pragma unroll
  for (int j = 0; j < 8; ++j) r[j] = (short)f2bf(s[j]);
  return r;
}

// ---------------------------------------------------------------------------
// Kernel 1/3: dual GEMM — EXACT R0 shape (measured-best 119.5 config:
// (24,8)/32n-per-wave, fp32 inputs, in-register bf16 cvt). Unchanged.
// ---------------------------------------------------------------------------
__global__ __launch_bounds__(256) void gemm_direct(
    const float* __restrict__ X, const float* __restrict__ WL,
    const float* __restrict__ WR, float* __restrict__ G,
    ushort_t* __restrict__ glb, ushort_t* __restrict__ grT,
    const int* __restrict__ adj, u64* __restrict__ mbits)
{
  const int t = threadIdx.x, wave = t >> 6, lane = t & 63;
  const int lm = lane & 15, q = lane >> 4;
  const int m0 = blockIdx.x * 16;
  const int n0 = (blockIdx.y * 4 + wave) * 32;
  const float* Wp = (n0 < 512) ? (WL + n0) : (WR + (n0 - 512));
  const float* Arow = X + (m0 + lm) * HF;

  f32x4 acc0 = {0.f, 0.f, 0.f, 0.f};
  f32x4 acc1 = {0.f, 0.f, 0.f, 0.f};
#pragma unroll 4
  for (int kc = 0; kc < 16; ++kc) {
    const int kbase = kc * 32 + q * 8;
    float4 a0 = *(const float4*)(Arow + kbase);
    float4 a1 = *(const float4*)(Arow + kbase + 4);
    float av8[8] = {a0.x, a0.y, a0.z, a0.w, a1.x, a1.y, a1.z, a1.w};
    short8 af = pack8(av8);
    float b0f[8], b1f[8];
#pragma unroll
    for (int j = 0; j < 8; ++j) {
      const float* r = Wp + (kbase + j) * HF;   // 64 lanes -> ~4 lines/instr
      b0f[j] = r[lm];
      b1f[j] = r[16 + lm];
    }
    short8 b0 = pack8(b0f);
    short8 b1 = pack8(b1f);
    acc0 = __builtin_amdgcn_mfma_f32_16x16x32_bf16(af, b0, acc0, 0, 0, 0);
    acc1 = __builtin_amdgcn_mfma_f32_16x16x32_bf16(af, b1, acc1, 0, 0, 0);
  }
  if (n0 < 512) {
#pragma unroll
    for (int r = 0; r < 4; ++r) {
      int m = m0 + q * 4 + r;
      glb[m * HF + n0 + lm]      = f2bf(acc0[r]);
      glb[m * HF + n0 + 16 + lm] = f2bf(acc1[r]);
    }
  } else {
#pragma unroll
    for (int r = 0; r < 4; ++r) {
      int m = m0 + q * 4 + r;
      G[m * 1024 + n0 + lm]      = acc0[r];
      G[m * 1024 + n0 + 16 + lm] = acc1[r];
    }
    int c0 = n0 - 512;
    uint2 p0, p1;
    p0.x = (uint32_t)f2bf(acc0[0]) | ((uint32_t)f2bf(acc0[1]) << 16);
    p0.y = (uint32_t)f2bf(acc0[2]) | ((uint32_t)f2bf(acc0[3]) << 16);
    p1.x = (uint32_t)f2bf(acc1[0]) | ((uint32_t)f2bf(acc1[1]) << 16);
    p1.y = (uint32_t)f2bf(acc1[2]) | ((uint32_t)f2bf(acc1[3]) << 16);
    *(uint2*)&grT[(c0 + lm) * 384 + m0 + q * 4]      = p0;
    *(uint2*)&grT[(c0 + 16 + lm) * 384 + m0 + q * 4] = p1;
  }
  // layer-0 only: adjacency bitmasks (self-loop OR'd in), by==0 blocks
  if (adj != nullptr && blockIdx.y == 0) {
    int rbase = (blockIdx.x * 4 + wave) * 4;
    for (int rr = 0; rr < 4; ++rr) {
      int row = rbase + rr;
#pragma unroll
      for (int w = 0; w < 6; ++w) {
        int j = w * 64 + lane;
        u64 m = __ballot(adj[row * N_NODES + j] != 0 || row == j);
        if (lane == 0) mbits[row * 6 + w] = m;
      }
    }
  }
}

// ---------------------------------------------------------------------------
// Kernel 2/4: fused GATv2 attention — R16: R0-proven body, IT halved 12->6.
// R2 counters showed 92% stall / 17% occupancy (1 block/CU, lockstep
// barriers). IT=6 drops LDS 80.6->69.6 KB -> 2 independent blocks/CU
// (12 waves/CU): one block's DMA/barrier stalls hide under the other's
// VALU phases. Inner logic byte-for-byte R0 except the IT-dependent bounds
// (mask words 36, bri threads 96, P-rows 6..15 zeroed, D-row guard <6) and
// the safe 4-accumulator phase-1 chain split.
// grid (64, 8), 384 thr.
// ---------------------------------------------------------------------------
template <int LAYER>
__global__ __launch_bounds__(384, 3) void attn_fused(
    const float* __restrict__ G, const ushort_t* __restrict__ glb,
    const ushort_t* __restrict__ grT, const u64* __restrict__ mbits,
    const float* __restrict__ resid_in, const float* __restrict__ avec,
    float* __restrict__ xcur_out, float* __restrict__ f_out)
{
  __shared__ __align__(16) char smem[49152];          // s_gl (DMA dst only)
  __shared__ float    s_e[IT][N_NODES];               // 9216 B
  __shared__ ushort_t s_pb[16][392];                  // 12544 B
  __shared__ float s_bri[IT];
  __shared__ u64   s_mask[IT][6];
  ushort_t (*s_gl)[64] = (ushort_t(*)[64])smem;

  const int t = threadIdx.x;
  const int i0 = blockIdx.x * IT, h = blockIdx.y;
  const int lane = t & 63, wave = t >> 6;
  const int lm = lane & 15, q = lane >> 4;

  // -- issue async global->LDS DMA first (8 x 16 B per thread) --
#pragma unroll
  for (int rep = 0; rep < 8; ++rep) {
    int idx = rep * 384 + t, row = idx >> 3, cl = idx & 7;
    int cg = cl ^ (row & 7);
    const ushort_t* gsrc = glb + row * HF + h * 64 + cg * 8;
    __builtin_amdgcn_global_load_lds(
        (const __attribute__((address_space(1))) uint32_t*)gsrc,
        (__attribute__((address_space(3))) uint32_t*)(smem + idx * 16),
        16, 0, 0);
  }

  // -- prefetch phase-3 B-fragments + epilogue resid (independent loads) --
  short8 bfrag[12];
  float  rres[4];
  if (wave < 4) {
    const ushort_t* Brow = grT + (h * 64 + wave * 16 + lm) * 384;
#pragma unroll
    for (int kc = 0; kc < 12; ++kc)
      bfrag[kc] = *(const short8*)&Brow[kc * 32 + q * 8];
#pragma unroll
    for (int r = 0; r < 4; ++r) {
      int row = q * 4 + r;
      if (row < IT)
        rres[r] = resid_in[(i0 + row) * HF + h * 64 + wave * 16 + lm];
    }
  }

  // -- overlapped with DMA: masks (36 u64) + bri dot + s_pb pad zeroing --
  if (t < IT * 6) ((u64*)s_mask)[t] = mbits[i0 * 6 + t];
  if (t >= 128 && t < 128 + IT * 16) {
    int u = t - 128, il = u >> 4, fg = u & 15;
    float4 g4 = *(const float4*)(G + (i0 + il) * 1024 + 512 + h * 64 + fg * 4);
    float4 a4 = *(const float4*)(avec + fg * 4);
    float s = a4.x * g4.x + a4.y * g4.y + a4.z * g4.z + a4.w * g4.w;
    s += __shfl_xor(s, 1); s += __shfl_xor(s, 2);
    s += __shfl_xor(s, 4); s += __shfl_xor(s, 8);
    if (fg == 0) s_bri[il] = s;
  }
#pragma unroll
  for (int r4 = 0; r4 < 16 - IT; ++r4) s_pb[IT + r4][t] = 0;  // zero P rows 6..15
  __syncthreads();   // barrier 1: drains DMA + overlap work

  // -- own j-row -> 64 VGPRs (chunk cg at slot cg^(t&7)); avec -> VGPRs --
  float gl[64], av[64];
  {
    const int sw = t & 7;
#pragma unroll
    for (int cg = 0; cg < 8; ++cg) {
      short8 v = *(const short8*)&s_gl[t][(cg ^ sw) * 8];
#pragma unroll
      for (int u2 = 0; u2 < 8; ++u2)
        gl[cg * 8 + u2] = bf2f_u((ushort_t)v[u2]);
    }
#pragma unroll
    for (int c = 0; c < 16; ++c) {
      float4 a4 = ((const float4*)avec)[c];
      av[c * 4] = a4.x; av[c * 4 + 1] = a4.y;
      av[c * 4 + 2] = a4.z; av[c * 4 + 3] = a4.w;
    }
  }
  float accl = 0.f;
#pragma unroll
  for (int f = 0; f < 64; ++f) accl += av[f] * gl[f];
  // no barrier: s_e is a separate region; each thread writes its own column

  // -- phase 1: scores, written straight to LDS (4 acc chains for latency) --
  const int jw = t >> 6, jb = t & 63;
#pragma unroll
  for (int il = 0; il < IT; ++il) {
    const float4* gr4 = (const float4*)(G + (i0 + il) * 1024 + 512 + h * 64);
    float c0 = 0.f, c1 = 0.f, c2 = 0.f, c3 = 0.f;
#pragma unroll
    for (int c = 0; c < 16; ++c) {
      float4 g4 = gr4[c];
      c0 += av[c * 4]     * fabsf(gl[c * 4]     + g4.x);
      c1 += av[c * 4 + 1] * fabsf(gl[c * 4 + 1] + g4.y);
      c2 += av[c * 4 + 2] * fabsf(gl[c * 4 + 2] + g4.z);
      c3 += av[c * 4 + 3] * fabsf(gl[c * 4 + 3] + g4.w);
    }
    float acc = (c0 + c1) + (c2 + c3);
    bool m = (s_mask[il][jw] >> jb) & 1;
    float e = 0.6f * (accl + s_bri[il]) + 0.4f * acc;
    s_e[il][t] = m ? e : -1e30f;
  }
  __syncthreads();   // barrier 2: scores visible to softmax waves

  // -- phase 2: softmax over j, one row per wave (6 waves, 6 rows) --
  if (wave < IT) {
    const int il = wave;
    float v[6];
    float mx = -1e30f;
#pragma unroll
    for (int c = 0; c < 6; ++c) { v[c] = s_e[il][lane + 64 * c]; mx = fmaxf(mx, v[c]); }
#pragma unroll
    for (int off = 32; off; off >>= 1) mx = fmaxf(mx, __shfl_xor(mx, off));
    float sum = 0.f;
#pragma unroll
    for (int c = 0; c < 6; ++c) { v[c] = __expf(v[c] - mx); sum += v[c]; }
#pragma unroll
    for (int off = 32; off; off >>= 1) sum += __shfl_xor(sum, off);
    float inv = 1.0f / sum;
#pragma unroll
    for (int c = 0; c < 6; ++c) s_pb[il][lane + 64 * c] = f2bf(v[c] * inv);
  }
  __syncthreads();   // barrier 3: P visible to MFMA waves

  // -- phase 3: MFMA (A from LDS, B + resid already in registers) --
  if (wave < 4) {
    f32x4 acc = {0.f, 0.f, 0.f, 0.f};
#pragma unroll
    for (int kc = 0; kc < 12; ++kc) {
      short8 af = *(const short8*)&s_pb[lm][kc * 32 + q * 8];
      acc = __builtin_amdgcn_mfma_f32_16x16x32_bf16(af, bfrag[kc], acc, 0, 0, 0);
    }
#pragma unroll
    for (int r = 0; r < 4; ++r) {
      int row = q * 4 + r;
      if (row < IT) {                               // D rows 0..5
        int i = i0 + row;
        int off = i * HF + h * 64 + wave * 16 + lm;
        float o = acc[r];
        if (LAYER == 0) {
          float oe = (o > 0.f) ? o : (__expf(o) - 1.f);   // ELU
          xcur_out[off] = rres[r] + oe;   // fp32 residual for layer 1
        } else {
          f_out[off] = rres[r] + o;       // final output, fp32
        }
      }
    }
  }
}

// ---------------------------------------------------------------------------
extern "C" void kernel_launch(void* const* d_in, const int* in_sizes, int n_in,
                              void* d_out, int out_size, void* d_ws, size_t ws_size,
                              hipStream_t stream) {
  const float* x   = (const float*)d_in[0];
  const int*   adj = (const int*)d_in[1];
  const float* Wl0 = (const float*)d_in[2];
  const float* Wr0 = (const float*)d_in[3];
  const float* a0  = (const float*)d_in[4];
  const float* Wl1 = (const float*)d_in[5];
  const float* Wr1 = (const float*)d_in[6];
  const float* a1  = (const float*)d_in[7];
  float* out = (float*)d_out;

  char* ws = (char*)d_ws;
  float*    G    = (float*)   (ws + 0L);            // 1.5 MB (gr half used)
  ushort_t* grT  = (ushort_t*)(ws + (2L << 20));    // 384 KB gr^T bf16
  ushort_t* glb  = (ushort_t*)(ws + (3L << 20));    // 384 KB gl bf16
  u64*      mbits= (u64*)     (ws + (4L << 20));    // 18 KB adjacency bits
  float*    xcur = (float*)   (ws + (5L << 20));    // 768 KB fp32 residual

  gemm_direct<<<dim3(24, 8), 256, 0, stream>>>(x, Wl0, Wr0, G, glb, grT,
                                               adj, mbits);
  attn_fused<0><<<dim3(64, 8), 384, 0, stream>>>(G, glb, grT, mbits, x, a0,
                                                 xcur, nullptr);
  gemm_direct<<<dim3(24, 8), 256, 0, stream>>>(xcur, Wl1, Wr1, G, glb, grT,
                                               nullptr, nullptr);
  attn_fused<1><<<dim3(64, 8), 384, 0, stream>>>(G, glb, grT, mbits, xcur, a1,
                                                 nullptr, out);
}

// Round 5
// 124.162 us; speedup vs baseline: 1.8526x; 1.0156x over previous
//
#include <hip/hip_runtime.h>
#include <hip/hip_bf16.h>
#include <stdint.h>

typedef unsigned short ushort_t;
typedef unsigned long long u64;
typedef __attribute__((ext_vector_type(8))) short short8;   // 8 bf16 (4 VGPRs)
typedef __attribute__((ext_vector_type(4))) float f32x4;

#define N_NODES 384
#define HF      512
#define IT      12        // i-rows per attention block: 32 tiles x 8 heads = 256

__device__ inline ushort_t f2bf(float f) {
  __hip_bfloat16 b = __float2bfloat16(f);
  return *reinterpret_cast<ushort_t*>(&b);
}
__device__ inline float bf2f_u(ushort_t u) {
  union { float f; uint32_t i; } v; v.i = ((uint32_t)u) << 16; return v.f;
}
__device__ inline short8 pack8(const float* s) {
  short8 r;
#pragma unroll
  for (int j = 0; j < 8; ++j) r[j] = (short)f2bf(s[j]);
  return r;
}

// ---------------------------------------------------------------------------
// Kernel 1/3: dual GEMM — R17: W tiles staged to LDS via async global_load_lds
// (double-buffered, BK=64). R0's W path was 256 scalar-broadcast VMEM
// loads/wave against poison-cold HBM (~900cy) at ~1 wave/SIMD = latency-
// exposed. Now: 8 x 16B DMA/thread/chunk (VGPR-free, all in flight), DMA of
// chunk c+1 issued right after the barrier that publishes chunk c, so it
// overlaps compute(c); the next barrier's vmcnt(0) drain is exactly the wait
// for chunk c+1. Granule-swizzled LDS placement (flip granule bit2 by k bit3)
// makes the per-kc fragment ds_read_b32s 2-way-bank-conflict-free with a
// loop-invariant address base. Fragment math / outputs / mbits identical to
// the measured-best R0 shape: grid (24,8), 256 thr, wave = 16m x 32n.
// ---------------------------------------------------------------------------
__global__ __launch_bounds__(256) void gemm_direct(
    const float* __restrict__ X, const float* __restrict__ WL,
    const float* __restrict__ WR, float* __restrict__ G,
    ushort_t* __restrict__ glb, ushort_t* __restrict__ grT,
    const int* __restrict__ adj, u64* __restrict__ mbits)
{
  __shared__ __align__(16) float wtile[2][64 * 128];   // 2 x 32 KB

  const int t = threadIdx.x, wave = t >> 6, lane = t & 63;
  const int lm = lane & 15, q = lane >> 4;
  const int m0 = blockIdx.x * 16;
  const int n0 = (blockIdx.y * 4 + wave) * 32;          // global col of wave
  // block-level W window: 128 cols, no WL/WR straddle (128 | 512)
  const float* Wsrc = (blockIdx.y < 4) ? (WL + blockIdx.y * 128)
                                       : (WR + (blockIdx.y - 4) * 128);
  const float* Arow = X + (m0 + lm) * HF;

  // loop-invariant swizzled column bases (floats within a 128-float k-row):
  // granule g' = g ^ ((q&1)<<2); bank spread: q even -> banks 0-15, q odd ->
  // 16-31 (2 lanes/bank = free).
  const int colf0 = (((wave * 8) + (lm >> 2)) ^ ((q & 1) << 2)) * 4 + (lm & 3);
  const int colf1 = (((wave * 8) + 4 + (lm >> 2)) ^ ((q & 1) << 2)) * 4 + (lm & 3);

  // -- DMA one 64k x 128n fp32 chunk into wtile[buf] (8 x 16 B per thread) --
  auto stage = [&](int c) {
    const float* base = Wsrc + c * 64 * HF;
    char* dst0 = (char*)&wtile[c & 1][0];
#pragma unroll
    for (int rep = 0; rep < 8; ++rep) {
      int idx = rep * 256 + t;                 // [0, 2048)
      int k = idx >> 5, gp = idx & 31;         // LDS row, LDS granule
      int gs = gp ^ (((k >> 3) & 1) << 2);     // swizzled global granule
      const float* src = base + k * HF + gs * 4;
      __builtin_amdgcn_global_load_lds(
          (const __attribute__((address_space(1))) uint32_t*)src,
          (__attribute__((address_space(3))) uint32_t*)(dst0 + idx * 16),
          16, 0, 0);
    }
  };

  f32x4 acc0 = {0.f, 0.f, 0.f, 0.f};
  f32x4 acc1 = {0.f, 0.f, 0.f, 0.f};

  stage(0);
  for (int c = 0; c < 8; ++c) {
    __syncthreads();                 // drains DMA of chunk c (vmcnt(0))
    if (c < 7) stage(c + 1);         // in flight during compute of chunk c
    const float* buf = &wtile[c & 1][0];
#pragma unroll
    for (int i = 0; i < 2; ++i) {
      const int kg = c * 64 + i * 32 + q * 8;  // global k base of fragment
      const int kl = i * 32 + q * 8;           // chunk-local k base
      float4 a0 = *(const float4*)(Arow + kg);
      float4 a1 = *(const float4*)(Arow + kg + 4);
      float av8[8] = {a0.x, a0.y, a0.z, a0.w, a1.x, a1.y, a1.z, a1.w};
      short8 af = pack8(av8);
      float b0f[8], b1f[8];
#pragma unroll
      for (int j = 0; j < 8; ++j) {
        const float* r = buf + (kl + j) * 128;
        b0f[j] = r[colf0];
        b1f[j] = r[colf1];
      }
      short8 b0 = pack8(b0f);
      short8 b1 = pack8(b1f);
      acc0 = __builtin_amdgcn_mfma_f32_16x16x32_bf16(af, b0, acc0, 0, 0, 0);
      acc1 = __builtin_amdgcn_mfma_f32_16x16x32_bf16(af, b1, acc1, 0, 0, 0);
    }
  }

  if (n0 < 512) {
#pragma unroll
    for (int r = 0; r < 4; ++r) {
      int m = m0 + q * 4 + r;
      glb[m * HF + n0 + lm]      = f2bf(acc0[r]);
      glb[m * HF + n0 + 16 + lm] = f2bf(acc1[r]);
    }
  } else {
#pragma unroll
    for (int r = 0; r < 4; ++r) {
      int m = m0 + q * 4 + r;
      G[m * 1024 + n0 + lm]      = acc0[r];
      G[m * 1024 + n0 + 16 + lm] = acc1[r];
    }
    int c0 = n0 - 512;
    uint2 p0, p1;
    p0.x = (uint32_t)f2bf(acc0[0]) | ((uint32_t)f2bf(acc0[1]) << 16);
    p0.y = (uint32_t)f2bf(acc0[2]) | ((uint32_t)f2bf(acc0[3]) << 16);
    p1.x = (uint32_t)f2bf(acc1[0]) | ((uint32_t)f2bf(acc1[1]) << 16);
    p1.y = (uint32_t)f2bf(acc1[2]) | ((uint32_t)f2bf(acc1[3]) << 16);
    *(uint2*)&grT[(c0 + lm) * 384 + m0 + q * 4]      = p0;
    *(uint2*)&grT[(c0 + 16 + lm) * 384 + m0 + q * 4] = p1;
  }
  // layer-0 only: adjacency bitmasks (self-loop OR'd in), by==0 blocks
  if (adj != nullptr && blockIdx.y == 0) {
    int rbase = (blockIdx.x * 4 + wave) * 4;
    for (int rr = 0; rr < 4; ++rr) {
      int row = rbase + rr;
#pragma unroll
      for (int w = 0; w < 6; ++w) {
        int j = w * 64 + lane;
        u64 m = __ballot(adj[row * N_NODES + j] != 0 || row == j);
        if (lane == 0) mbits[row * 6 + w] = m;
      }
    }
  }
}

// ---------------------------------------------------------------------------
// Kernel 2/4: fused GATv2 attention — R0-proven IT=12 body, grid (32,8),
// 384 thr, 1 block/CU. R17's single change: G rows (3 KB) staged to s_gr by
// the bri threads during the DMA-overlap window; phase-1 reads LDS
// broadcasts instead of (poison-cold) global. Plus the R16-proven 4-acc
// phase-1 chains. Everything else byte-identical to the 119.5 baseline.
// LDS 83.8 KB -> still 1 block/CU.
// ---------------------------------------------------------------------------
template <int LAYER>
__global__ __launch_bounds__(384) void attn_fused(
    const float* __restrict__ G, const ushort_t* __restrict__ glb,
    const ushort_t* __restrict__ grT, const u64* __restrict__ mbits,
    const float* __restrict__ resid_in, const float* __restrict__ avec,
    float* __restrict__ xcur_out, float* __restrict__ f_out)
{
  __shared__ __align__(16) char smem[49152];          // s_gl (DMA dst only)
  __shared__ float    s_e[IT][N_NODES];               // 18432 B
  __shared__ ushort_t s_pb[16][392];                  // 12544 B
  __shared__ float    s_gr[IT][64];                   // 3072 B (staged G rows)
  __shared__ float s_bri[IT];
  __shared__ u64   s_mask[IT][6];
  ushort_t (*s_gl)[64] = (ushort_t(*)[64])smem;

  const int t = threadIdx.x;
  const int i0 = blockIdx.x * IT, h = blockIdx.y;
  const int lane = t & 63, wave = t >> 6;
  const int lm = lane & 15, q = lane >> 4;

  // -- issue async global->LDS DMA first (8 x 16 B per thread) --
#pragma unroll
  for (int rep = 0; rep < 8; ++rep) {
    int idx = rep * 384 + t, row = idx >> 3, cl = idx & 7;
    int cg = cl ^ (row & 7);
    const ushort_t* gsrc = glb + row * HF + h * 64 + cg * 8;
    __builtin_amdgcn_global_load_lds(
        (const __attribute__((address_space(1))) uint32_t*)gsrc,
        (__attribute__((address_space(3))) uint32_t*)(smem + idx * 16),
        16, 0, 0);
  }

  // -- prefetch phase-3 B-fragments + epilogue resid (independent loads) --
  short8 bfrag[12];
  float  rres[4];
  if (wave < 4) {
    const ushort_t* Brow = grT + (h * 64 + wave * 16 + lm) * 384;
#pragma unroll
    for (int kc = 0; kc < 12; ++kc)
      bfrag[kc] = *(const short8*)&Brow[kc * 32 + q * 8];
    if (q < 3) {
#pragma unroll
      for (int r = 0; r < 4; ++r)
        rres[r] = resid_in[(i0 + q * 4 + r) * HF + h * 64 + wave * 16 + lm];
    }
  }

  // -- overlapped with DMA: masks + bri dot + s_gr stage + s_pb zeroing --
  if (t < 72) ((u64*)s_mask)[t] = mbits[i0 * 6 + t];
  if (t >= 128 && t < 320) {
    int u = t - 128, il = u >> 4, fg = u & 15;
    float4 g4 = *(const float4*)(G + (i0 + il) * 1024 + 512 + h * 64 + fg * 4);
    float4 a4 = *(const float4*)(avec + fg * 4);
    *(float4*)&s_gr[il][fg * 4] = g4;               // stage for phase-1
    float s = a4.x * g4.x + a4.y * g4.y + a4.z * g4.z + a4.w * g4.w;
    s += __shfl_xor(s, 1); s += __shfl_xor(s, 2);
    s += __shfl_xor(s, 4); s += __shfl_xor(s, 8);
    if (fg == 0) s_bri[il] = s;
  }
#pragma unroll
  for (int r4 = 0; r4 < 4; ++r4) s_pb[IT + r4][t] = 0;  // zero P rows 12..15
  __syncthreads();   // barrier 1: drains DMA + overlap work

  // -- own j-row -> 64 VGPRs (chunk cg at slot cg^(t&7)); avec -> VGPRs --
  float gl[64], av[64];
  {
    const int sw = t & 7;
#pragma unroll
    for (int cg = 0; cg < 8; ++cg) {
      short8 v = *(const short8*)&s_gl[t][(cg ^ sw) * 8];
#pragma unroll
      for (int u2 = 0; u2 < 8; ++u2)
        gl[cg * 8 + u2] = bf2f_u((ushort_t)v[u2]);
    }
#pragma unroll
    for (int c = 0; c < 16; ++c) {
      float4 a4 = ((const float4*)avec)[c];
      av[c * 4] = a4.x; av[c * 4 + 1] = a4.y;
      av[c * 4 + 2] = a4.z; av[c * 4 + 3] = a4.w;
    }
  }
  float accl = 0.f;
#pragma unroll
  for (int f = 0; f < 64; ++f) accl += av[f] * gl[f];
  // no barrier: s_e is a separate region; each thread writes its own column

  // -- phase 1: scores from LDS-staged G rows (4 acc chains) --
  const int jw = t >> 6, jb = t & 63;
#pragma unroll
  for (int il = 0; il < IT; ++il) {
    float c0 = 0.f, c1 = 0.f, c2 = 0.f, c3 = 0.f;
#pragma unroll
    for (int c = 0; c < 16; ++c) {
      float4 g4 = *(const float4*)&s_gr[il][c * 4];
      c0 += av[c * 4]     * fabsf(gl[c * 4]     + g4.x);
      c1 += av[c * 4 + 1] * fabsf(gl[c * 4 + 1] + g4.y);
      c2 += av[c * 4 + 2] * fabsf(gl[c * 4 + 2] + g4.z);
      c3 += av[c * 4 + 3] * fabsf(gl[c * 4 + 3] + g4.w);
    }
    float acc = (c0 + c1) + (c2 + c3);
    bool m = (s_mask[il][jw] >> jb) & 1;
    float e = 0.6f * (accl + s_bri[il]) + 0.4f * acc;
    s_e[il][t] = m ? e : -1e30f;
  }
  __syncthreads();   // barrier 2: scores visible to softmax waves

  // -- phase 2: softmax over j per row; write normalized P bf16 --
#pragma unroll
  for (int rep = 0; rep < 2; ++rep) {
    int il = wave * 2 + rep;
    float v[6];
    float mx = -1e30f;
#pragma unroll
    for (int c = 0; c < 6; ++c) { v[c] = s_e[il][lane + 64 * c]; mx = fmaxf(mx, v[c]); }
#pragma unroll
    for (int off = 32; off; off >>= 1) mx = fmaxf(mx, __shfl_xor(mx, off));
    float sum = 0.f;
#pragma unroll
    for (int c = 0; c < 6; ++c) { v[c] = __expf(v[c] - mx); sum += v[c]; }
#pragma unroll
    for (int off = 32; off; off >>= 1) sum += __shfl_xor(sum, off);
    float inv = 1.0f / sum;
#pragma unroll
    for (int c = 0; c < 6; ++c) s_pb[il][lane + 64 * c] = f2bf(v[c] * inv);
  }
  __syncthreads();   // barrier 3: P visible to MFMA waves

  // -- phase 3: MFMA (A from LDS, B + resid already in registers) --
  if (wave < 4) {
    f32x4 acc = {0.f, 0.f, 0.f, 0.f};
#pragma unroll
    for (int kc = 0; kc < 12; ++kc) {
      short8 af = *(const short8*)&s_pb[lm][kc * 32 + q * 8];
      acc = __builtin_amdgcn_mfma_f32_16x16x32_bf16(af, bfrag[kc], acc, 0, 0, 0);
    }
    if (q < 3) {                                    // D rows 0..11
#pragma unroll
      for (int r = 0; r < 4; ++r) {
        int i = i0 + q * 4 + r;
        int off = i * HF + h * 64 + wave * 16 + lm;
        float o = acc[r];
        if (LAYER == 0) {
          float oe = (o > 0.f) ? o : (__expf(o) - 1.f);   // ELU
          xcur_out[off] = rres[r] + oe;   // fp32 residual for layer 1
        } else {
          f_out[off] = rres[r] + o;       // final output, fp32
        }
      }
    }
  }
}

// ---------------------------------------------------------------------------
extern "C" void kernel_launch(void* const* d_in, const int* in_sizes, int n_in,
                              void* d_out, int out_size, void* d_ws, size_t ws_size,
                              hipStream_t stream) {
  const float* x   = (const float*)d_in[0];
  const int*   adj = (const int*)d_in[1];
  const float* Wl0 = (const float*)d_in[2];
  const float* Wr0 = (const float*)d_in[3];
  const float* a0  = (const float*)d_in[4];
  const float* Wl1 = (const float*)d_in[5];
  const float* Wr1 = (const float*)d_in[6];
  const float* a1  = (const float*)d_in[7];
  float* out = (float*)d_out;

  char* ws = (char*)d_ws;
  float*    G    = (float*)   (ws + 0L);            // 1.5 MB (gr half used)
  ushort_t* grT  = (ushort_t*)(ws + (2L << 20));    // 384 KB gr^T bf16
  ushort_t* glb  = (ushort_t*)(ws + (3L << 20));    // 384 KB gl bf16
  u64*      mbits= (u64*)     (ws + (4L << 20));    // 18 KB adjacency bits
  float*    xcur = (float*)   (ws + (5L << 20));    // 768 KB fp32 residual

  gemm_direct<<<dim3(24, 8), 256, 0, stream>>>(x, Wl0, Wr0, G, glb, grT,
                                               adj, mbits);
  attn_fused<0><<<dim3(32, 8), 384, 0, stream>>>(G, glb, grT, mbits, x, a0,
                                                 xcur, nullptr);
  gemm_direct<<<dim3(24, 8), 256, 0, stream>>>(xcur, Wl1, Wr1, G, glb, grT,
                                               nullptr, nullptr);
  attn_fused<1><<<dim3(32, 8), 384, 0, stream>>>(G, glb, grT, mbits, xcur, a1,
                                                 nullptr, out);
}

// Round 6
// 119.280 us; speedup vs baseline: 1.9284x; 1.0409x over previous
//
#include <hip/hip_runtime.h>
#include <hip/hip_bf16.h>
#include <stdint.h>

typedef unsigned short ushort_t;
typedef unsigned long long u64;
typedef __attribute__((ext_vector_type(8))) short short8;   // 8 bf16 (4 VGPRs)
typedef __attribute__((ext_vector_type(4))) float f32x4;

#define N_NODES 384
#define HF      512
#define IT      12        // i-rows per attention block: 32 tiles x 8 heads = 256

__device__ inline ushort_t f2bf(float f) {
  __hip_bfloat16 b = __float2bfloat16(f);
  return *reinterpret_cast<ushort_t*>(&b);
}
__device__ inline float bf2f_u(ushort_t u) {
  union { float f; uint32_t i; } v; v.i = ((uint32_t)u) << 16; return v.f;
}
__device__ inline short8 pack8(const float* s) {
  short8 r;
#pragma unroll
  for (int j = 0; j < 8; ++j) r[j] = (short)f2bf(s[j]);
  return r;
}

// ---------------------------------------------------------------------------
// Kernel 1/3: dual GEMM, raw fp32 inputs, in-register bf16 cvt (R10 shape —
// (24,8)/32n-per-wave; R8+R12 both showed the 16n/384-block variant is ~+3
// µs/launch worse: per-block fixed cost beats TLP at this size).
// R13 (bf16-prepack, strictly less work) and R17 (LDS-staged W pipeline)
// both measured WORSE/neutral: this barrier-free form with unroll-4 MLP is
// the best cold-memory latency-hider tested. Do not "improve" without
// per-kernel counters proving a stall here.
// G[m][n] = sum_k X[m][k]*W[k][n], n in [0,1024), W = [WL | WR] fp32.
//  n <  512 (gl): glb bf16 [m][n]
//  n >= 512 (gr): G fp32 [m][512+n'] and grT bf16 [n'][m] (k-contig)
// grid (24, 8), 256 threads = 4 waves; wave computes 16m x 32n.
// Layer 0 extra: adjacency bitmasks (by==0 blocks).
// ---------------------------------------------------------------------------
__global__ __launch_bounds__(256) void gemm_direct(
    const float* __restrict__ X, const float* __restrict__ WL,
    const float* __restrict__ WR, float* __restrict__ G,
    ushort_t* __restrict__ glb, ushort_t* __restrict__ grT,
    const int* __restrict__ adj, u64* __restrict__ mbits)
{
  const int t = threadIdx.x, wave = t >> 6, lane = t & 63;
  const int lm = lane & 15, q = lane >> 4;
  const int m0 = blockIdx.x * 16;
  const int n0 = (blockIdx.y * 4 + wave) * 32;
  const float* Wp = (n0 < 512) ? (WL + n0) : (WR + (n0 - 512));
  const float* Arow = X + (m0 + lm) * HF;

  f32x4 acc0 = {0.f, 0.f, 0.f, 0.f};
  f32x4 acc1 = {0.f, 0.f, 0.f, 0.f};
#pragma unroll 4
  for (int kc = 0; kc < 16; ++kc) {
    const int kbase = kc * 32 + q * 8;
    float4 a0 = *(const float4*)(Arow + kbase);
    float4 a1 = *(const float4*)(Arow + kbase + 4);
    float av8[8] = {a0.x, a0.y, a0.z, a0.w, a1.x, a1.y, a1.z, a1.w};
    short8 af = pack8(av8);
    float b0f[8], b1f[8];
#pragma unroll
    for (int j = 0; j < 8; ++j) {
      const float* r = Wp + (kbase + j) * HF;   // 64 lanes -> ~4 lines/instr
      b0f[j] = r[lm];
      b1f[j] = r[16 + lm];
    }
    short8 b0 = pack8(b0f);
    short8 b1 = pack8(b1f);
    acc0 = __builtin_amdgcn_mfma_f32_16x16x32_bf16(af, b0, acc0, 0, 0, 0);
    acc1 = __builtin_amdgcn_mfma_f32_16x16x32_bf16(af, b1, acc1, 0, 0, 0);
  }
  if (n0 < 512) {
#pragma unroll
    for (int r = 0; r < 4; ++r) {
      int m = m0 + q * 4 + r;
      glb[m * HF + n0 + lm]      = f2bf(acc0[r]);
      glb[m * HF + n0 + 16 + lm] = f2bf(acc1[r]);
    }
  } else {
#pragma unroll
    for (int r = 0; r < 4; ++r) {
      int m = m0 + q * 4 + r;
      G[m * 1024 + n0 + lm]      = acc0[r];
      G[m * 1024 + n0 + 16 + lm] = acc1[r];
    }
    int c0 = n0 - 512;
    uint2 p0, p1;
    p0.x = (uint32_t)f2bf(acc0[0]) | ((uint32_t)f2bf(acc0[1]) << 16);
    p0.y = (uint32_t)f2bf(acc0[2]) | ((uint32_t)f2bf(acc0[3]) << 16);
    p1.x = (uint32_t)f2bf(acc1[0]) | ((uint32_t)f2bf(acc1[1]) << 16);
    p1.y = (uint32_t)f2bf(acc1[2]) | ((uint32_t)f2bf(acc1[3]) << 16);
    *(uint2*)&grT[(c0 + lm) * 384 + m0 + q * 4]      = p0;
    *(uint2*)&grT[(c0 + 16 + lm) * 384 + m0 + q * 4] = p1;
  }
  // layer-0 only: adjacency bitmasks (self-loop OR'd in), by==0 blocks
  if (adj != nullptr && blockIdx.y == 0) {
    int rbase = (blockIdx.x * 4 + wave) * 4;
    for (int rr = 0; rr < 4; ++rr) {
      int row = rbase + rr;
#pragma unroll
      for (int w = 0; w < 6; ++w) {
        int j = w * 64 + lane;
        u64 m = __ballot(adj[row * N_NODES + j] != 0 || row == j);
        if (lane == 0) mbits[row * 6 + w] = m;
      }
    }
  }
}

// ---------------------------------------------------------------------------
// Kernel 2/4: fused GATv2 attention (R10 + 3-barrier restructure).
// Block = (12-row i-tile, head), 384 thr, grid (32,8) = 256 blocks = 1/CU.
// NOTE (R14-R17): grid is exactly 1 block/CU, so LDS cuts buy no occupancy;
// IT=6 (2 blocks/CU) and 768-thr variants measured worse; s_gr staging of G
// measured worse in combination. This exact body is the measured optimum.
// (1) s_e/s_pb do not alias s_gl -> one barrier removed; (2) phase-3
// B-fragments (12 x short8) + epilogue resid prefetched into registers at
// kernel start, so nothing after the last barrier touches global; (3) s_pb
// pad-row zeroing in the DMA-overlap window. LDS ~80.6 KB -> 1 block/CU.
// ---------------------------------------------------------------------------
template <int LAYER>
__global__ __launch_bounds__(384) void attn_fused(
    const float* __restrict__ G, const ushort_t* __restrict__ glb,
    const ushort_t* __restrict__ grT, const u64* __restrict__ mbits,
    const float* __restrict__ resid_in, const float* __restrict__ avec,
    float* __restrict__ xcur_out, float* __restrict__ f_out)
{
  __shared__ __align__(16) char smem[49152];          // s_gl (DMA dst only)
  __shared__ float    s_e[IT][N_NODES];               // 18432 B (separate!)
  __shared__ ushort_t s_pb[16][392];                  // 12544 B
  __shared__ float s_bri[IT];
  __shared__ u64   s_mask[IT][6];
  ushort_t (*s_gl)[64] = (ushort_t(*)[64])smem;

  const int t = threadIdx.x;
  const int i0 = blockIdx.x * IT, h = blockIdx.y;
  const int lane = t & 63, wave = t >> 6;
  const int lm = lane & 15, q = lane >> 4;

  // -- issue async global->LDS DMA first (8 x 16 B per thread) --
#pragma unroll
  for (int rep = 0; rep < 8; ++rep) {
    int idx = rep * 384 + t, row = idx >> 3, cl = idx & 7;
    int cg = cl ^ (row & 7);
    const ushort_t* gsrc = glb + row * HF + h * 64 + cg * 8;
    __builtin_amdgcn_global_load_lds(
        (const __attribute__((address_space(1))) uint32_t*)gsrc,
        (__attribute__((address_space(3))) uint32_t*)(smem + idx * 16),
        16, 0, 0);
  }

  // -- prefetch phase-3 B-fragments + epilogue resid (independent loads) --
  short8 bfrag[12];
  float  rres[4];
  if (wave < 4) {
    const ushort_t* Brow = grT + (h * 64 + wave * 16 + lm) * 384;
#pragma unroll
    for (int kc = 0; kc < 12; ++kc)
      bfrag[kc] = *(const short8*)&Brow[kc * 32 + q * 8];
    if (q < 3) {
#pragma unroll
      for (int r = 0; r < 4; ++r)
        rres[r] = resid_in[(i0 + q * 4 + r) * HF + h * 64 + wave * 16 + lm];
    }
  }

  // -- overlapped with DMA: masks (72 u64) + bri dot + s_pb pad zeroing --
  if (t < 72) ((u64*)s_mask)[t] = mbits[i0 * 6 + t];
  if (t >= 128 && t < 320) {
    int u = t - 128, il = u >> 4, fg = u & 15;
    float4 g4 = *(const float4*)(G + (i0 + il) * 1024 + 512 + h * 64 + fg * 4);
    float4 a4 = *(const float4*)(avec + fg * 4);
    float s = a4.x * g4.x + a4.y * g4.y + a4.z * g4.z + a4.w * g4.w;
    s += __shfl_xor(s, 1); s += __shfl_xor(s, 2);
    s += __shfl_xor(s, 4); s += __shfl_xor(s, 8);
    if (fg == 0) s_bri[il] = s;
  }
#pragma unroll
  for (int r4 = 0; r4 < 4; ++r4) s_pb[IT + r4][t] = 0;  // zero P rows 12..15
  __syncthreads();   // barrier 1: drains DMA + overlap work

  // -- own j-row -> 64 VGPRs (chunk cg at slot cg^(t&7)); avec -> VGPRs --
  float gl[64], av[64];
  {
    const int sw = t & 7;
#pragma unroll
    for (int cg = 0; cg < 8; ++cg) {
      short8 v = *(const short8*)&s_gl[t][(cg ^ sw) * 8];
#pragma unroll
      for (int u2 = 0; u2 < 8; ++u2)
        gl[cg * 8 + u2] = bf2f_u((ushort_t)v[u2]);
    }
#pragma unroll
    for (int c = 0; c < 16; ++c) {
      float4 a4 = ((const float4*)avec)[c];
      av[c * 4] = a4.x; av[c * 4 + 1] = a4.y;
      av[c * 4 + 2] = a4.z; av[c * 4 + 3] = a4.w;
    }
  }
  float accl = 0.f;
#pragma unroll
  for (int f = 0; f < 64; ++f) accl += av[f] * gl[f];
  // no barrier: s_e is a separate region; each thread writes its own column

  // -- phase 1: scores, written straight to LDS --
  const int jw = t >> 6, jb = t & 63;
#pragma unroll
  for (int il = 0; il < IT; ++il) {
    const float4* gr4 = (const float4*)(G + (i0 + il) * 1024 + 512 + h * 64);
    float acc = 0.f;
#pragma unroll
    for (int c = 0; c < 16; ++c) {
      float4 g4 = gr4[c];
      acc += av[c * 4]     * fabsf(gl[c * 4]     + g4.x);
      acc += av[c * 4 + 1] * fabsf(gl[c * 4 + 1] + g4.y);
      acc += av[c * 4 + 2] * fabsf(gl[c * 4 + 2] + g4.z);
      acc += av[c * 4 + 3] * fabsf(gl[c * 4 + 3] + g4.w);
    }
    bool m = (s_mask[il][jw] >> jb) & 1;
    float e = 0.6f * (accl + s_bri[il]) + 0.4f * acc;
    s_e[il][t] = m ? e : -1e30f;
  }
  __syncthreads();   // barrier 2: scores visible to softmax waves

  // -- phase 2: softmax over j per row; write normalized P bf16 --
#pragma unroll
  for (int rep = 0; rep < 2; ++rep) {
    int il = wave * 2 + rep;
    float v[6];
    float mx = -1e30f;
#pragma unroll
    for (int c = 0; c < 6; ++c) { v[c] = s_e[il][lane + 64 * c]; mx = fmaxf(mx, v[c]); }
#pragma unroll
    for (int off = 32; off; off >>= 1) mx = fmaxf(mx, __shfl_xor(mx, off));
    float sum = 0.f;
#pragma unroll
    for (int c = 0; c < 6; ++c) { v[c] = __expf(v[c] - mx); sum += v[c]; }
#pragma unroll
    for (int off = 32; off; off >>= 1) sum += __shfl_xor(sum, off);
    float inv = 1.0f / sum;
#pragma unroll
    for (int c = 0; c < 6; ++c) s_pb[il][lane + 64 * c] = f2bf(v[c] * inv);
  }
  __syncthreads();   // barrier 3: P visible to MFMA waves

  // -- phase 3: MFMA (A from LDS, B + resid already in registers) --
  if (wave < 4) {
    f32x4 acc = {0.f, 0.f, 0.f, 0.f};
#pragma unroll
    for (int kc = 0; kc < 12; ++kc) {
      short8 af = *(const short8*)&s_pb[lm][kc * 32 + q * 8];
      acc = __builtin_amdgcn_mfma_f32_16x16x32_bf16(af, bfrag[kc], acc, 0, 0, 0);
    }
    if (q < 3) {                                    // D rows 0..11
#pragma unroll
      for (int r = 0; r < 4; ++r) {
        int i = i0 + q * 4 + r;
        int off = i * HF + h * 64 + wave * 16 + lm;
        float o = acc[r];
        if (LAYER == 0) {
          float oe = (o > 0.f) ? o : (__expf(o) - 1.f);   // ELU
          xcur_out[off] = rres[r] + oe;   // fp32 residual for layer 1
        } else {
          f_out[off] = rres[r] + o;       // final output, fp32
        }
      }
    }
  }
}

// ---------------------------------------------------------------------------
extern "C" void kernel_launch(void* const* d_in, const int* in_sizes, int n_in,
                              void* d_out, int out_size, void* d_ws, size_t ws_size,
                              hipStream_t stream) {
  const float* x   = (const float*)d_in[0];
  const int*   adj = (const int*)d_in[1];
  const float* Wl0 = (const float*)d_in[2];
  const float* Wr0 = (const float*)d_in[3];
  const float* a0  = (const float*)d_in[4];
  const float* Wl1 = (const float*)d_in[5];
  const float* Wr1 = (const float*)d_in[6];
  const float* a1  = (const float*)d_in[7];
  float* out = (float*)d_out;

  char* ws = (char*)d_ws;
  float*    G    = (float*)   (ws + 0L);            // 1.5 MB (gr half used)
  ushort_t* grT  = (ushort_t*)(ws + (2L << 20));    // 384 KB gr^T bf16
  ushort_t* glb  = (ushort_t*)(ws + (3L << 20));    // 384 KB gl bf16
  u64*      mbits= (u64*)     (ws + (4L << 20));    // 18 KB adjacency bits
  float*    xcur = (float*)   (ws + (5L << 20));    // 768 KB fp32 residual

  gemm_direct<<<dim3(24, 8), 256, 0, stream>>>(x, Wl0, Wr0, G, glb, grT,
                                               adj, mbits);
  attn_fused<0><<<dim3(32, 8), 384, 0, stream>>>(G, glb, grT, mbits, x, a0,
                                                 xcur, nullptr);
  gemm_direct<<<dim3(24, 8), 256, 0, stream>>>(xcur, Wl1, Wr1, G, glb, grT,
                                               nullptr, nullptr);
  attn_fused<1><<<dim3(32, 8), 768 / 2, 0, stream>>>(G, glb, grT, mbits, xcur, a1,
                                                 nullptr, out);
}